// Round 14
// baseline (312.924 us; speedup 1.0000x reference)
//
#include <hip/hip_runtime.h>
#include <hip/hip_bf16.h>

#define CL 2
#define CB 4
#define CT 1024
#define CD 256
#define CH 4
#define CM 1024
#define CHD (CH * CD)      // 1024
#define NROW (CB * CT)     // 4096

typedef unsigned short ushort_t;
typedef __attribute__((ext_vector_type(8))) short short8v;   // 8 bf16 (4 VGPR)
typedef __attribute__((ext_vector_type(4))) float float4v;   // MFMA C/D frag

#define LOG2E 1.44269504088896f

__device__ __forceinline__ float bf2f(unsigned short u) {
    return __uint_as_float(((unsigned int)u) << 16);
}
__device__ __forceinline__ unsigned short f2bf(float f) {
    unsigned int x = __float_as_uint(f);
    return (unsigned short)((x + 0x7fffu + ((x >> 16) & 1u)) >> 16);
}

// ---------------------------------------------------------------------------
// Input-dtype detection (2048 elems; fp32-underlying -> ~430 anomalies, bf16 0)
// ---------------------------------------------------------------------------
__global__ __launch_bounds__(256) void detect_kernel(
    const ushort_t* __restrict__ w, int n, int* __restrict__ flag)
{
    __shared__ int red[256];
    int c = 0;
    for (int i = threadIdx.x; i < n; i += 256) {
        float v = bf2f(w[i]);
        if (!(fabsf(v) <= 1e6f)) c++;
    }
    red[threadIdx.x] = c;
    __syncthreads();
    for (int s = 128; s > 0; s >>= 1) {
        if (threadIdx.x < s) red[threadIdx.x] += red[threadIdx.x + s];
        __syncthreads();
    }
    if (threadIdx.x == 0) flag[0] = (red[0] < 8) ? 1 : 0;
}

// ---------------------------------------------------------------------------
// Merged prepass (r14: one dispatch instead of two):
//  blocks 0..2047: transpose Wq/Wk/Wv/W1 ([L][256][1024] -> T)
//    x = bx&31 (col tile), y = (bx>>5)&7 (row tile), z = bx>>8 = which*2+l
//  blocks 2048..3071: in_convert (queries -> bf16 xa, 1024 elems/block)
// ---------------------------------------------------------------------------
__global__ __launch_bounds__(256) void prepass_kernel(
    const void* __restrict__ Wq, const void* __restrict__ Wk,
    const void* __restrict__ Wv, const void* __restrict__ W1,
    ushort_t* __restrict__ wqkvT, ushort_t* __restrict__ w1T,
    const void* __restrict__ queries, ushort_t* __restrict__ xa,
    const int* __restrict__ flagp)
{
    const int fbf = *flagp;
    const int bx = blockIdx.x;
    const int tid = threadIdx.x;

    if (bx >= 2048) {
        const long i = ((long)(bx - 2048) * 256 + tid) << 2;
        if (fbf) {
            *reinterpret_cast<ushort4*>(xa + i) =
                *reinterpret_cast<const ushort4*>((const ushort_t*)queries + i);
        } else {
            float4 f = *reinterpret_cast<const float4*>((const float*)queries + i);
            ushort4 u;
            u.x = f2bf(f.x); u.y = f2bf(f.y); u.z = f2bf(f.z); u.w = f2bf(f.w);
            *reinterpret_cast<ushort4*>(xa + i) = u;
        }
        return;
    }

    const int z = bx >> 8;
    const int which = z >> 1, l = z & 1;
    const void* in = (which == 0) ? Wq : (which == 1) ? Wk
                   : (which == 2) ? Wv : W1;
    ushort_t* out = (which < 3)
        ? wqkvT + (long)l * 3072 * 256 + (long)which * 1024 * 256
        : w1T + (long)l * 1024 * 256;
    const long zi = (long)l * 262144;

    __shared__ float tile[32][33];
    const int r0 = ((bx >> 5) & 7) * 32;
    const int c0 = (bx & 31) * 32;
    const int tx = tid & 31;
    const int ty = tid >> 5;
#pragma unroll
    for (int i = 0; i < 32; i += 8) {
        const long idx = zi + (long)(r0 + ty + i) * 1024 + c0 + tx;
        tile[ty + i][tx] = fbf ? bf2f(((const ushort_t*)in)[idx])
                               : ((const float*)in)[idx];
    }
    __syncthreads();
#pragma unroll
    for (int i = 0; i < 32; i += 8)
        out[(long)(c0 + ty + i) * 256 + r0 + tx] = f2bf(tile[tx][ty + i]);
}

// ---------------------------------------------------------------------------
// Merged QKV projection (BK=64, r14: 32 MFMA per barrier-pair) + Wo/W2
// transpose. Blocks 0..767 qkv 128x128 tiles; 768..1279 tconv2.
// ---------------------------------------------------------------------------
__global__ __launch_bounds__(256) void qkv_tconv(
    const ushort_t* __restrict__ A, const ushort_t* __restrict__ B,
    const void* __restrict__ bq, const void* __restrict__ bk,
    const void* __restrict__ bv, ushort_t* __restrict__ qk,
    ushort_t* __restrict__ vT,
    const void* __restrict__ Wo, const void* __restrict__ W2,
    ushort_t* __restrict__ wscr,
    long boff, long ioff, const int* __restrict__ flagp)
{
    __shared__ __align__(16) ushort_t As[128 * 72];
    __shared__ __align__(16) ushort_t Bs[128 * 72];
    __shared__ float tile[32][33];

    const int fbf = *flagp;
    const int bx = blockIdx.x;
    const int tid = threadIdx.x;

    if (bx >= 768) {
        const int t = bx - 768;
        const int zx = t & 7;
        const int zy = (t >> 3) & 31;
        const int zz = t >> 8;
        const void* in = zz ? W2 : Wo;
        ushort_t* out = wscr + (long)zz * 262144;
        const int r0 = zy * 32;
        const int c0 = zx * 32;
        const int tx = tid & 31;
        const int ty = tid >> 5;
#pragma unroll
        for (int i = 0; i < 32; i += 8) {
            const long idx = ioff + (long)(r0 + ty + i) * 256 + c0 + tx;
            tile[ty + i][tx] = fbf ? bf2f(((const ushort_t*)in)[idx])
                                   : ((const float*)in)[idx];
        }
        __syncthreads();
#pragma unroll
        for (int i = 0; i < 32; i += 8)
            out[(long)(c0 + ty + i) * 1024 + r0 + tx] = f2bf(tile[tx][ty + i]);
        return;
    }

    const int nt = bx % 24;
    const int mt = bx / 24;
    const long m0 = (long)mt * 128;
    const long n0 = (long)nt * 128;

    const int wave = tid >> 6;
    const int lane = tid & 63;
    const int quad = lane >> 4;
    const int lrow = lane & 15;
    const int wm = (wave >> 1) * 64;
    const int wn = (wave & 1) * 64;

    float4v acc[4][4];
#pragma unroll
    for (int i = 0; i < 4; ++i)
#pragma unroll
        for (int j = 0; j < 4; ++j)
            acc[i][j] = (float4v){0.f, 0.f, 0.f, 0.f};

    for (int k0 = 0; k0 < 256; k0 += 64) {
        __syncthreads();
#pragma unroll
        for (int p = 0; p < 4; ++p) {
            const int c = p * 256 + tid;
            const int row = c >> 3;
            const int kc = (c & 7) << 3;
            *reinterpret_cast<short8v*>(&As[row * 72 + kc]) =
                *reinterpret_cast<const short8v*>(&A[(m0 + row) * 256 + k0 + kc]);
            *reinterpret_cast<short8v*>(&Bs[row * 72 + kc]) =
                *reinterpret_cast<const short8v*>(&B[(n0 + row) * 256 + k0 + kc]);
        }
        __syncthreads();

#pragma unroll
        for (int kk = 0; kk < 2; ++kk) {
            short8v af[4], bfv[4];
#pragma unroll
            for (int i = 0; i < 4; ++i) {
                af[i]  = *reinterpret_cast<const short8v*>(
                    &As[(wm + i * 16 + lrow) * 72 + kk * 32 + quad * 8]);
                bfv[i] = *reinterpret_cast<const short8v*>(
                    &Bs[(wn + i * 16 + lrow) * 72 + kk * 32 + quad * 8]);
            }
#pragma unroll
            for (int mi = 0; mi < 4; ++mi)
#pragma unroll
                for (int ni = 0; ni < 4; ++ni)
                    acc[mi][ni] = __builtin_amdgcn_mfma_f32_16x16x32_bf16(
                        af[mi], bfv[ni], acc[mi][ni], 0, 0, 0);
        }
    }

#pragma unroll
    for (int mi = 0; mi < 4; ++mi) {
#pragma unroll
        for (int ni = 0; ni < 4; ++ni) {
            const long col = n0 + wn + ni * 16 + lrow;
            const long row0 = m0 + wm + mi * 16 + quad * 4;
            const void* bp;
            long bn;
            if (col < 1024)      { bp = bq; bn = col; }
            else if (col < 2048) { bp = bk; bn = col - 1024; }
            else                 { bp = bv; bn = col - 2048; }
            const float bias = fbf ? bf2f(((const ushort_t*)bp)[boff + bn])
                                   : ((const float*)bp)[boff + bn];
            if (col < 2048) {
#pragma unroll
                for (int r = 0; r < 4; ++r)
                    qk[(row0 + r) * 2048 + col] = f2bf(acc[mi][ni][r] + bias);
            } else {
                const long d = col - 2048;
                const long addr = ((row0 >> 10) << 2) * 262144 + d * 1024 + (row0 & 1023);
                ushort4 u;
                u.x = f2bf(acc[mi][ni][0] + bias);
                u.y = f2bf(acc[mi][ni][1] + bias);
                u.z = f2bf(acc[mi][ni][2] + bias);
                u.w = f2bf(acc[mi][ni][3] + bias);
                *reinterpret_cast<ushort4*>(&vT[addr]) = u;
            }
        }
    }
}

// ---------------------------------------------------------------------------
// mgemm64s: 64x64-tile split-K GEMM -> fp32 partials, BK=64 (proven r13).
// AMODE 1: attention-partial combine with hoisted scales.
// ---------------------------------------------------------------------------
template <int AMODE>
__global__ __launch_bounds__(256) void mgemm64s(
    const ushort_t* __restrict__ A, const ushort_t* __restrict__ Ap1,
    const float2* __restrict__ ml, const ushort_t* __restrict__ B,
    float* __restrict__ P, int K2, int lda, int ldb)
{
    const int z = blockIdx.z;
    const long m0 = (long)blockIdx.y * 64;
    const long n0 = (long)blockIdx.x * 64;
    const int k_beg = z * K2;

    __shared__ __align__(16) ushort_t As[64 * 72];
    __shared__ __align__(16) ushort_t Bs[64 * 72];

    const int tid = threadIdx.x;
    const int wave = tid >> 6;
    const int lane = tid & 63;
    const int quad = lane >> 4;
    const int lrow = lane & 15;
    const int wm = (wave >> 1) * 32;
    const int wn = (wave & 1) * 32;

    const int ar = tid >> 2;
    const int ak = (tid & 3) << 3;

    float s0h[2] = {0.f, 0.f}, s1h[2] = {0.f, 0.f};
    if constexpr (AMODE == 1) {
        const long m = m0 + ar;
        const int bhbase = ((int)(m >> 10) << 2);
        const int trow = (int)(m & 1023);
        const int h0 = k_beg >> 8;
#pragma unroll
        for (int i = 0; i < 2; ++i) {
            const int bh = bhbase + h0 + i;
            const float2 v0 = ml[bh * 1024 + trow];
            const float2 v1 = ml[(16 + bh) * 1024 + trow];
            const float mm = fmaxf(v0.x, v1.x);
            const float a0 = exp2f(v0.x - mm);
            const float a1 = exp2f(v1.x - mm);
            const float inv = 1.0f / (v0.y * a0 + v1.y * a1);
            s0h[i] = a0 * inv;
            s1h[i] = a1 * inv;
        }
    }

    float4v acc[2][2];
#pragma unroll
    for (int i = 0; i < 2; ++i)
#pragma unroll
        for (int j = 0; j < 2; ++j)
            acc[i][j] = (float4v){0.f, 0.f, 0.f, 0.f};

    for (int k0 = k_beg; k0 < k_beg + K2; k0 += 64) {
        __syncthreads();
#pragma unroll
        for (int p = 0; p < 2; ++p) {
            const int kc = p * 32 + ak;
            if constexpr (AMODE == 0) {
                *reinterpret_cast<short8v*>(&As[ar * 72 + kc]) =
                    *reinterpret_cast<const short8v*>(&A[(m0 + ar) * (long)lda + k0 + kc]);
            } else {
                const long m = m0 + ar;
                const int hi = ((k0 + kc) >> 8) - (k_beg >> 8);
                const float s0 = s0h[hi], s1 = s1h[hi];
                const ushort4 u0a = *reinterpret_cast<const ushort4*>(&A[m * 1024 + k0 + kc]);
                const ushort4 u0b = *reinterpret_cast<const ushort4*>(&A[m * 1024 + k0 + kc + 4]);
                const ushort4 u1a = *reinterpret_cast<const ushort4*>(&Ap1[m * 1024 + k0 + kc]);
                const ushort4 u1b = *reinterpret_cast<const ushort4*>(&Ap1[m * 1024 + k0 + kc + 4]);
                short8v t8;
                t8[0] = (short)f2bf(bf2f(u0a.x) * s0 + bf2f(u1a.x) * s1);
                t8[1] = (short)f2bf(bf2f(u0a.y) * s0 + bf2f(u1a.y) * s1);
                t8[2] = (short)f2bf(bf2f(u0a.z) * s0 + bf2f(u1a.z) * s1);
                t8[3] = (short)f2bf(bf2f(u0a.w) * s0 + bf2f(u1a.w) * s1);
                t8[4] = (short)f2bf(bf2f(u0b.x) * s0 + bf2f(u1b.x) * s1);
                t8[5] = (short)f2bf(bf2f(u0b.y) * s0 + bf2f(u1b.y) * s1);
                t8[6] = (short)f2bf(bf2f(u0b.z) * s0 + bf2f(u1b.z) * s1);
                t8[7] = (short)f2bf(bf2f(u0b.w) * s0 + bf2f(u1b.w) * s1);
                *reinterpret_cast<short8v*>(&As[ar * 72 + kc]) = t8;
            }
            *reinterpret_cast<short8v*>(&Bs[ar * 72 + kc]) =
                *reinterpret_cast<const short8v*>(&B[(n0 + ar) * (long)ldb + k0 + kc]);
        }
        __syncthreads();

#pragma unroll
        for (int kk = 0; kk < 2; ++kk) {
            short8v af[2], bfv[2];
#pragma unroll
            for (int i = 0; i < 2; ++i) {
                af[i]  = *reinterpret_cast<const short8v*>(
                    &As[(wm + i * 16 + lrow) * 72 + kk * 32 + quad * 8]);
                bfv[i] = *reinterpret_cast<const short8v*>(
                    &Bs[(wn + i * 16 + lrow) * 72 + kk * 32 + quad * 8]);
            }
#pragma unroll
            for (int mi = 0; mi < 2; ++mi)
#pragma unroll
                for (int ni = 0; ni < 2; ++ni)
                    acc[mi][ni] = __builtin_amdgcn_mfma_f32_16x16x32_bf16(
                        af[mi], bfv[ni], acc[mi][ni], 0, 0, 0);
        }
    }

    float* Pz = P + (long)z * NROW * CD;
#pragma unroll
    for (int mi = 0; mi < 2; ++mi)
#pragma unroll
        for (int ni = 0; ni < 2; ++ni) {
            const long col = n0 + wn + ni * 16 + lrow;
            const long row0 = m0 + wm + mi * 16 + quad * 4;
#pragma unroll
            for (int r = 0; r < 4; ++r)
                Pz[(row0 + r) * CD + col] = acc[mi][ni][r];
        }
}

// ---------------------------------------------------------------------------
// mgemm128b: 128x64-tile full-K GEMM (MLP1), BK=64. Grid (N/64, M/128) = 512
// blocks = 2/CU with 16 MFMA per barrier-pair per wave (r13's 64x64 had 8).
// Wave w owns rows wm=w*32 (2 m-tiles) x all 64 cols (4 n-tiles).
// ---------------------------------------------------------------------------
template <int RELU>
__global__ __launch_bounds__(256) void mgemm128b(
    const ushort_t* __restrict__ A, const ushort_t* __restrict__ B,
    const void* __restrict__ bias, ushort_t* __restrict__ C,
    int K, int lda, int ldb, int ldc, long boff,
    const int* __restrict__ flagp)
{
    const long m0 = (long)blockIdx.y * 128;
    const long n0 = (long)blockIdx.x * 64;

    __shared__ __align__(16) ushort_t As[128 * 72];
    __shared__ __align__(16) ushort_t Bs[64 * 72];

    const int tid = threadIdx.x;
    const int wave = tid >> 6;
    const int lane = tid & 63;
    const int quad = lane >> 4;
    const int lrow = lane & 15;
    const int wm = wave * 32;

    float4v acc[2][4];
#pragma unroll
    for (int i = 0; i < 2; ++i)
#pragma unroll
        for (int j = 0; j < 4; ++j)
            acc[i][j] = (float4v){0.f, 0.f, 0.f, 0.f};

    for (int k0 = 0; k0 < K; k0 += 64) {
        __syncthreads();
#pragma unroll
        for (int p = 0; p < 4; ++p) {
            const int c = p * 256 + tid;
            const int row = c >> 3;
            const int kc = (c & 7) << 3;
            *reinterpret_cast<short8v*>(&As[row * 72 + kc]) =
                *reinterpret_cast<const short8v*>(&A[(m0 + row) * (long)lda + k0 + kc]);
        }
#pragma unroll
        for (int p = 0; p < 2; ++p) {
            const int c = p * 256 + tid;
            const int row = c >> 3;
            const int kc = (c & 7) << 3;
            *reinterpret_cast<short8v*>(&Bs[row * 72 + kc]) =
                *reinterpret_cast<const short8v*>(&B[(n0 + row) * (long)ldb + k0 + kc]);
        }
        __syncthreads();

#pragma unroll
        for (int kk = 0; kk < 2; ++kk) {
            short8v af[2], bfv[4];
#pragma unroll
            for (int i = 0; i < 2; ++i)
                af[i] = *reinterpret_cast<const short8v*>(
                    &As[(wm + i * 16 + lrow) * 72 + kk * 32 + quad * 8]);
#pragma unroll
            for (int i = 0; i < 4; ++i)
                bfv[i] = *reinterpret_cast<const short8v*>(
                    &Bs[(i * 16 + lrow) * 72 + kk * 32 + quad * 8]);
#pragma unroll
            for (int mi = 0; mi < 2; ++mi)
#pragma unroll
                for (int ni = 0; ni < 4; ++ni)
                    acc[mi][ni] = __builtin_amdgcn_mfma_f32_16x16x32_bf16(
                        af[mi], bfv[ni], acc[mi][ni], 0, 0, 0);
        }
    }

    const int fbf = *flagp;
#pragma unroll
    for (int mi = 0; mi < 2; ++mi)
#pragma unroll
        for (int ni = 0; ni < 4; ++ni) {
            const long col = n0 + ni * 16 + lrow;
            const long row0 = m0 + wm + mi * 16 + quad * 4;
            const float bv = fbf ? bf2f(((const ushort_t*)bias)[boff + col])
                                 : ((const float*)bias)[boff + col];
#pragma unroll
            for (int r = 0; r < 4; ++r) {
                float v = acc[mi][ni][r] + bv;
                if (RELU) v = fmaxf(v, 0.f);
                C[(row0 + r) * (long)ldc + col] = f2bf(v);
            }
        }
}

// ---------------------------------------------------------------------------
// Flash attention v6 (proven r11-r13, ~48 us): 32-key tiles, K+V LDS,
// S^T softmax, lazy rescale, packed Ps stores.
// ---------------------------------------------------------------------------
__global__ __launch_bounds__(256) void flash_attn(
    const ushort_t* __restrict__ qk, const ushort_t* __restrict__ vT,
    ushort_t* __restrict__ op0, ushort_t* __restrict__ op1,
    float2* __restrict__ ml)
{
    const int bx = blockIdx.x;
    const int bh = bx & 15;
    const int qt = (bx >> 4) & 15;
    const int ck = bx >> 8;
    const int b = bh >> 2, h = bh & 3;

    __shared__ __align__(16) ushort_t Ks[32 * 264];
    __shared__ __align__(16) ushort_t Vs[256 * 40];
    __shared__ __align__(16) ushort_t Ps[4][16 * 40];

    const int tid = threadIdx.x;
    const int wave = tid >> 6;
    const int lane = tid & 63;
    const int quad = lane >> 4;
    const int lrow = lane & 15;

    const long qrow0 = (long)b * CT + qt * 64;
    const int qcol = h * 256;
    const int kcol = 1024 + h * 256;
    const long vbase = (long)bh * 256 * 1024;
    const float SC = 0.0625f * LOG2E;

    short8v qf[8];
#pragma unroll
    for (int kk = 0; kk < 8; ++kk)
        qf[kk] = *reinterpret_cast<const short8v*>(
            &qk[(qrow0 + wave * 16 + lrow) * 2048 + qcol + kk * 32 + quad * 8]);

    float mrun = -1e30f, lrun = 0.f;
    float4v oacc[16];
#pragma unroll
    for (int i = 0; i < 16; ++i) oacc[i] = (float4v){0.f, 0.f, 0.f, 0.f};

    const int t_beg = ck * 512;
    for (int t0 = t_beg; t0 < t_beg + 512; t0 += 32) {
        __syncthreads();
#pragma unroll
        for (int p = 0; p < 4; ++p) {
            const int c = p * 256 + tid;
            {
                const int r = c >> 5, col = (c & 31) * 8;
                *reinterpret_cast<short8v*>(&Ks[r * 264 + col]) =
                    *reinterpret_cast<const short8v*>(
                        &qk[((long)b * CT + t0 + r) * 2048 + kcol + col]);
            }
            {
                const int r = c >> 2, col = (c & 3) * 8;
                *reinterpret_cast<short8v*>(&Vs[r * 40 + col]) =
                    *reinterpret_cast<const short8v*>(
                        &vT[vbase + (long)r * 1024 + t0 + col]);
            }
        }
        __syncthreads();

        float4v sacc[2];
        sacc[0] = (float4v){0.f, 0.f, 0.f, 0.f};
        sacc[1] = (float4v){0.f, 0.f, 0.f, 0.f};
#pragma unroll
        for (int kk = 0; kk < 8; ++kk) {
#pragma unroll
            for (int ni = 0; ni < 2; ++ni) {
                short8v bk = *reinterpret_cast<const short8v*>(
                    &Ks[(ni * 16 + lrow) * 264 + kk * 32 + quad * 8]);
                sacc[ni] = __builtin_amdgcn_mfma_f32_16x16x32_bf16(
                    bk, qf[kk], sacc[ni], 0, 0, 0);   // swapped -> S^T
            }
        }
#pragma unroll
        for (int ni = 0; ni < 2; ++ni)
#pragma unroll
            for (int r = 0; r < 4; ++r)
                sacc[ni][r] *= SC;

        float mx = fmaxf(fmaxf(fmaxf(sacc[0][0], sacc[0][1]),
                               fmaxf(sacc[0][2], sacc[0][3])),
                         fmaxf(fmaxf(sacc[1][0], sacc[1][1]),
                               fmaxf(sacc[1][2], sacc[1][3])));
        mx = fmaxf(mx, __shfl_xor(mx, 16));
        mx = fmaxf(mx, __shfl_xor(mx, 32));

        if (__ballot(mx > mrun + 1.0f) != 0ull) {
            const float mnew = fmaxf(mrun, mx);
            const float alpha = exp2f(mrun - mnew);
            mrun = mnew;
            lrun *= alpha;
            float a4[4];
#pragma unroll
            for (int r = 0; r < 4; ++r)
                a4[r] = __shfl(alpha, quad * 4 + r);
#pragma unroll
            for (int ni = 0; ni < 16; ++ni)
#pragma unroll
                for (int r = 0; r < 4; ++r)
                    oacc[ni][r] *= a4[r];
        }

        float s = 0.f;
#pragma unroll
        for (int ni = 0; ni < 2; ++ni) {
            ushort4 pu;
#pragma unroll
            for (int r = 0; r < 4; ++r) {
                const float pv = exp2f(sacc[ni][r] - mrun);
                s += pv;
                (&pu.x)[r] = f2bf(pv);
            }
            *reinterpret_cast<ushort4*>(
                &Ps[wave][lrow * 40 + ni * 16 + quad * 4]) = pu;
        }
        s += __shfl_xor(s, 16);
        s += __shfl_xor(s, 32);
        lrun += s;

        {
            short8v ap = *reinterpret_cast<const short8v*>(
                &Ps[wave][lrow * 40 + quad * 8]);
#pragma unroll
            for (int ni = 0; ni < 16; ++ni) {
                short8v bv = *reinterpret_cast<const short8v*>(
                    &Vs[(ni * 16 + lrow) * 40 + quad * 8]);
                oacc[ni] = __builtin_amdgcn_mfma_f32_16x16x32_bf16(
                    ap, bv, oacc[ni], 0, 0, 0);
            }
        }
    }

    if (quad == 0)
        ml[((ck << 4) + bh) * 1024 + qt * 64 + wave * 16 + lrow] =
            make_float2(mrun, lrun);

    ushort_t* op = ck ? op1 : op0;
#pragma unroll
    for (int ni = 0; ni < 16; ++ni)
#pragma unroll
        for (int r = 0; r < 4; ++r)
            op[(qrow0 + wave * 16 + quad * 4 + r) * 1024 + (h << 8) + ni * 16 + lrow]
                = f2bf(oacc[ni][r]);
}

// ---------------------------------------------------------------------------
// ln_p v2 (r14): wave-per-row, ZERO barriers (r13 version: 1 elem/thread,
// 8 __syncthreads tree rounds). 4 rows/block, 4 cols/lane, 6 shfl_xor steps.
// Grid NROW/4 = 1024. FINAL=1 writes d_out in flag dtype.
// ---------------------------------------------------------------------------
template <int FINAL>
__global__ __launch_bounds__(256) void ln_p(
    const float* __restrict__ p, const void* __restrict__ gb, long gboff,
    const ushort_t* __restrict__ res, const void* __restrict__ sc,
    const void* __restrict__ bi, void* __restrict__ out, long loff,
    const int* __restrict__ flagp)
{
    const int fbf = *flagp;
    const int wave = threadIdx.x >> 6;
    const int lane = threadIdx.x & 63;
    const long base = ((long)blockIdx.x * 4 + wave) * CD;
    const int c0 = lane << 2;

    const float4 p0 = *reinterpret_cast<const float4*>(&p[base + c0]);
    const float4 p1 = *reinterpret_cast<const float4*>(&p[(long)NROW * CD + base + c0]);
    const ushort4 rs = *reinterpret_cast<const ushort4*>(&res[base + c0]);
    float g[4];
    if (fbf) {
        const ushort4 gu = *reinterpret_cast<const ushort4*>(
            &((const ushort_t*)gb)[gboff + c0]);
        g[0] = bf2f(gu.x); g[1] = bf2f(gu.y); g[2] = bf2f(gu.z); g[3] = bf2f(gu.w);
    } else {
        const float4 gf = *reinterpret_cast<const float4*>(
            &((const float*)gb)[gboff + c0]);
        g[0] = gf.x; g[1] = gf.y; g[2] = gf.z; g[3] = gf.w;
    }
    float x[4];
    x[0] = p0.x + p1.x + g[0] + bf2f(rs.x);
    x[1] = p0.y + p1.y + g[1] + bf2f(rs.y);
    x[2] = p0.z + p1.z + g[2] + bf2f(rs.z);
    x[3] = p0.w + p1.w + g[3] + bf2f(rs.w);

    float s1 = (x[0] + x[1]) + (x[2] + x[3]);
    float s2 = (x[0] * x[0] + x[1] * x[1]) + (x[2] * x[2] + x[3] * x[3]);
#pragma unroll
    for (int sh = 1; sh < 64; sh <<= 1) {
        s1 += __shfl_xor(s1, sh);
        s2 += __shfl_xor(s2, sh);
    }
    const float mean = s1 * (1.0f / CD);
    const float var = s2 * (1.0f / CD) - mean * mean;
    const float rstd = rsqrtf(var + 1e-5f);

    float scv[4], biv[4];
    if (fbf) {
        const ushort4 su = *reinterpret_cast<const ushort4*>(
            &((const ushort_t*)sc)[loff + c0]);
        const ushort4 bu = *reinterpret_cast<const ushort4*>(
            &((const ushort_t*)bi)[loff + c0]);
        scv[0] = bf2f(su.x); scv[1] = bf2f(su.y); scv[2] = bf2f(su.z); scv[3] = bf2f(su.w);
        biv[0] = bf2f(bu.x); biv[1] = bf2f(bu.y); biv[2] = bf2f(bu.z); biv[3] = bf2f(bu.w);
    } else {
        const float4 sf = *reinterpret_cast<const float4*>(&((const float*)sc)[loff + c0]);
        const float4 bf = *reinterpret_cast<const float4*>(&((const float*)bi)[loff + c0]);
        scv[0] = sf.x; scv[1] = sf.y; scv[2] = sf.z; scv[3] = sf.w;
        biv[0] = bf.x; biv[1] = bf.y; biv[2] = bf.z; biv[3] = bf.w;
    }
    float y[4];
#pragma unroll
    for (int j = 0; j < 4; ++j)
        y[j] = (x[j] - mean) * rstd * scv[j] + biv[j];

    if (FINAL && !fbf) {
        float4 f;
        f.x = y[0]; f.y = y[1]; f.z = y[2]; f.w = y[3];
        *reinterpret_cast<float4*>(&((float*)out)[base + c0]) = f;
    } else {
        ushort4 u;
        u.x = f2bf(y[0]); u.y = f2bf(y[1]); u.z = f2bf(y[2]); u.w = f2bf(y[3]);
        *reinterpret_cast<ushort4*>(&((ushort_t*)out)[base + c0]) = u;
    }
}

// ---------------------------------------------------------------------------
// Orchestration. ws = 47.25 MB + 256 B. Dispatches: 2 + 7/layer x 2 = 16.
// ---------------------------------------------------------------------------
extern "C" void kernel_launch(void* const* d_in, const int* in_sizes, int n_in,
                              void* d_out, int out_size, void* d_ws, size_t ws_size,
                              hipStream_t stream)
{
    const void* queries = d_in[0];
    const void* Wq = d_in[1];  const void* bq = d_in[2];
    const void* Wk = d_in[3];  const void* bk = d_in[4];
    const void* Wv = d_in[5];  const void* bv = d_in[6];
    const void* Wo = d_in[7];  const void* bo = d_in[8];
    const void* ln1s = d_in[9];  const void* ln1b = d_in[10];
    const void* W1 = d_in[11]; const void* b1 = d_in[12];
    const void* W2 = d_in[13]; const void* b2 = d_in[14];
    const void* ln2s = d_in[15]; const void* ln2b = d_in[16];

    char* p = (char*)d_ws;
    int* flagp = (int*)p;             p += 256;
    ushort_t* wqkvT = (ushort_t*)p;   p += (long)CL * 3072 * 256 * 2;  // 3 MB
    ushort_t* w1T   = (ushort_t*)p;   p += (long)CL * 1024 * 256 * 2;  // 1 MB
    ushort_t* wscr  = (ushort_t*)p;   p += (long)2 * 256 * 1024 * 2;   // 1 MB
    ushort_t* xa    = (ushort_t*)p;   p += (long)NROW * CD * 2;        // 2 MB
    ushort_t* qk    = (ushort_t*)p;   p += (long)NROW * 2048 * 2;      // 16 MB
    ushort_t* vT    = (ushort_t*)p;   p += (long)16 * 256 * 1024 * 2;  // 8 MB
    ushort_t* op0   = (ushort_t*)p;   p += (long)NROW * 1024 * 2;      // 8 MB
    ushort_t* op1   = (ushort_t*)p;   p += (long)NROW * 1024 * 2;      // 8 MB
    float2*   ml    = (float2*)p;     p += (long)2 * 16 * 1024 * 8;    // 0.25 MB
    ushort_t* h     = vT;             // MLP hidden reuses vT
    float*    pgem  = (float*)qk;     // fp32 partials reuse qk (dead post-flash)

    detect_kernel<<<1, 256, 0, stream>>>((const ushort_t*)Wq, 2048, flagp);
    prepass_kernel<<<3072, 256, 0, stream>>>(
        Wq, Wk, Wv, W1, wqkvT, w1T, queries, xa, flagp);

    for (int l = 0; l < CL; ++l) {
        // 1) merged QKV projection (BK=64) + Wo/W2 transpose
        qkv_tconv<<<dim3(1280, 1, 1), 256, 0, stream>>>(
            xa, wqkvT + (long)l * 3072 * 256, bq, bk, bv, qk, vT,
            Wo, W2, wscr, (long)l * 1024, (long)l * 1024 * 256, flagp);
        // 2) flash attention (512 blocks, lazy rescale)
        flash_attn<<<512, 256, 0, stream>>>(qk, vT, op0, op1, ml);
        // 3) O projection with fused partial-combine (BK=64, hoisted scales)
        mgemm64s<1><<<dim3(4, 64, 2), 256, 0, stream>>>(
            op0, op1, ml, wscr, pgem, 512, 1024, 1024);
        // 4) xa = LN(pgem0+pgem1 + bo + xa)  (wave-per-row, no barriers)
        ln_p<0><<<NROW / 4, 256, 0, stream>>>(pgem, bo, (long)l * 256, xa,
                                              ln1s, ln1b, xa, (long)l * 256, flagp);
        // 5) h = relu(xa @ w1T^T + b1)  (128x64 tiles, 512 blocks)
        mgemm128b<1><<<dim3(16, 32, 1), 256, 0, stream>>>(
            xa, w1T + (long)l * 1024 * 256, b1, h,
            256, 256, 256, 1024, (long)l * 1024, flagp);
        // 6) MLP2 -> fp32 pgem  (BK=64)
        mgemm64s<0><<<dim3(4, 64, 2), 256, 0, stream>>>(
            h, nullptr, nullptr, wscr + 262144, pgem, 512, 1024, 1024);
        // 7) LN(pgem0+pgem1 + b2 + xa): final layer writes d_out directly
        if (l == CL - 1)
            ln_p<1><<<NROW / 4, 256, 0, stream>>>(pgem, b2, (long)l * 256, xa,
                                                  ln2s, ln2b, d_out, (long)l * 256, flagp);
        else
            ln_p<0><<<NROW / 4, 256, 0, stream>>>(pgem, b2, (long)l * 256, xa,
                                                  ln2s, ln2b, xa, (long)l * 256, flagp);
    }
}